// Round 2
// baseline (1227.193 us; speedup 1.0000x reference)
//
#include <hip/hip_runtime.h>

#define EMBED   256
#define NGRAPH  256

// ---------------- fused path: 8 blocks x 256 threads per graph ----------------
#define PB      8                    // blocks per graph
#define TBLOCK  256                  // threads per block (4 waves)
#define NWB     (TBLOCK / 64)        // 4 waves per block
#define WPG     (PB * NWB)           // 32 waves cooperating per graph

// ---------------- legacy fallback (round-1 structure) ----------------
#define P       4
#define BLOCK1  512
#define NW1     (BLOCK1 / 64)
#define WPG1    (P * NW1)
#define BLOCK3  256
#define NB3     2048

__device__ __forceinline__ void find_range(const int* __restrict__ batch,
                                           int nNodes, int g, int& n0, int& n1) {
  int a = 0, b = nNodes;
  while (a < b) { int m = (a + b) >> 1; (batch[m] < g) ? (a = m + 1) : (b = m); }
  n0 = a;
  b = nNodes;
  while (a < b) { int m = (a + b) >> 1; (batch[m] <= g) ? (a = m + 1) : (b = m); }
  n1 = a;
}

__global__ void init_cnt(int* __restrict__ cnt) { cnt[threadIdx.x] = 0; }

// ---------------------------------------------------------------------------
// Fully fused, single heavy dispatch. Grid = 2048 blocks of 256 threads =
// exactly 32 waves/CU (co-resident: <=64 VGPR via launch_bounds, ~7 KB LDS),
// so per-graph spin-on-flag sync is safe. Phases stagger across graphs ->
// HBM read and write streams overlap chip-wide; no kernel-boundary drains.
// ---------------------------------------------------------------------------
__global__ __launch_bounds__(TBLOCK, 8) void fused_all(
    const float* __restrict__ x, const int* __restrict__ batch,
    const float* __restrict__ in_w, const float* __restrict__ in_b,
    const float* __restrict__ out_w, const float* __restrict__ out_b,
    float* __restrict__ out, int* __restrict__ cnt,
    float* __restrict__ rows, float* __restrict__ partial, int nNodes) {
  const int g  = blockIdx.x >> 3;          // PB == 8
  const int p  = blockIdx.x & (PB - 1);
  const int t  = threadIdx.x;
  const int q  = t >> 6;
  const int c4 = t & 63;

  int n0, n1;
  find_range(batch, nNodes, g, n0, n1);
  const int cn = n1 - n0;

  // ---- phase A: strided partial sum (wave slot w of 32 for this graph) ----
  const float4* xp = (const float4*)x + (size_t)n0 * (EMBED / 4) + c4;
  const int w = p * NWB + q;
  float4 a0 = make_float4(0.f, 0.f, 0.f, 0.f);
  float4 a1 = make_float4(0.f, 0.f, 0.f, 0.f);
  int i = w;
  for (; i + 7 * WPG < cn; i += 8 * WPG) {
    float4 v0 = xp[(size_t)(i          ) * (EMBED / 4)];
    float4 v1 = xp[(size_t)(i + 1 * WPG) * (EMBED / 4)];
    float4 v2 = xp[(size_t)(i + 2 * WPG) * (EMBED / 4)];
    float4 v3 = xp[(size_t)(i + 3 * WPG) * (EMBED / 4)];
    float4 v4 = xp[(size_t)(i + 4 * WPG) * (EMBED / 4)];
    float4 v5 = xp[(size_t)(i + 5 * WPG) * (EMBED / 4)];
    float4 v6 = xp[(size_t)(i + 6 * WPG) * (EMBED / 4)];
    float4 v7 = xp[(size_t)(i + 7 * WPG) * (EMBED / 4)];
    a0.x += v0.x + v1.x; a0.y += v0.y + v1.y; a0.z += v0.z + v1.z; a0.w += v0.w + v1.w;
    a1.x += v2.x + v3.x; a1.y += v2.y + v3.y; a1.z += v2.z + v3.z; a1.w += v2.w + v3.w;
    a0.x += v4.x + v5.x; a0.y += v4.y + v5.y; a0.z += v4.z + v5.z; a0.w += v4.w + v5.w;
    a1.x += v6.x + v7.x; a1.y += v6.y + v7.y; a1.z += v6.z + v7.z; a1.w += v6.w + v7.w;
  }
  for (; i < cn; i += WPG) {
    float4 v = xp[(size_t)i * (EMBED / 4)];
    a0.x += v.x; a0.y += v.y; a0.z += v.z; a0.w += v.w;
  }
  a0.x += a1.x; a0.y += a1.y; a0.z += a1.z; a0.w += a1.w;

  __shared__ float4 red4[NWB][EMBED / 4];  // == float [NWB][EMBED]
  __shared__ float sg[EMBED];
  __shared__ float sv[EMBED];
  red4[q][c4] = a0;
  __syncthreads();
  {
    const float* rf = (const float*)red4;
    float s = 0.f;
#pragma unroll
    for (int k = 0; k < NWB; ++k) s += rf[k * EMBED + t];
    partial[((size_t)p * NGRAPH + g) * EMBED + t] = s;
  }
  __threadfence();          // make partial stores device-visible
  __syncthreads();          // all threads' fences precede t0's release
  if (t == 0)
    __hip_atomic_fetch_add(&cnt[g], 1, __ATOMIC_ACQ_REL, __HIP_MEMORY_SCOPE_AGENT);

  // ---- phase B: team leader reduces partials, mean, two matvecs ----
  if (p == 0) {
    if (t == 0)
      while (__hip_atomic_load(&cnt[g], __ATOMIC_ACQUIRE, __HIP_MEMORY_SCOPE_AGENT) < PB)
        __builtin_amdgcn_s_sleep(8);
    __syncthreads();

    const float inv = 1.0f / fmaxf((float)cn, 1.0f);
    float s = 0.f;
#pragma unroll
    for (int pp = 0; pp < PB; ++pp)
      s += partial[((size_t)pp * NGRAPH + g) * EMBED + t];
    sg[t] = s * inv;
    __syncthreads();

    float acc = in_b[2 * EMBED + t];
    const float4* wrow = (const float4*)(in_w + (size_t)(2 * EMBED + t) * EMBED);
#pragma unroll 8
    for (int k4 = 0; k4 < EMBED / 4; ++k4) {
      const float4 wv = wrow[k4];
      const int k = k4 * 4;
      acc += sg[k] * wv.x + sg[k + 1] * wv.y + sg[k + 2] * wv.z + sg[k + 3] * wv.w;
    }
    sv[t] = acc;
    __syncthreads();

    float acc2 = out_b[t];
    const float4* wrow2 = (const float4*)(out_w + (size_t)t * EMBED);
#pragma unroll 8
    for (int k4 = 0; k4 < EMBED / 4; ++k4) {
      const float4 wv = wrow2[k4];
      const int k = k4 * 4;
      acc2 += sv[k] * wv.x + sv[k + 1] * wv.y + sv[k + 2] * wv.z + sv[k + 3] * wv.w;
    }
    rows[(size_t)g * EMBED + t] = acc2;
    __threadfence();
    __syncthreads();
    if (t == 0)
      __hip_atomic_fetch_add(&cnt[g], 1, __ATOMIC_ACQ_REL, __HIP_MEMORY_SCOPE_AGENT);
  } else {
    if (t == 0)
      while (__hip_atomic_load(&cnt[g], __ATOMIC_ACQUIRE, __HIP_MEMORY_SCOPE_AGENT) < PB + 1)
        __builtin_amdgcn_s_sleep(8);
    __syncthreads();
  }

  // ---- phase C: broadcast graph row to this team's share of nodes ----
  const float4 oval = ((const float4*)(rows + (size_t)g * EMBED))[c4];
  float4* op = (float4*)out + c4;
  int n = n0 + w;
  for (; n + 3 * WPG < n1; n += 4 * WPG) {
    op[(size_t)(n          ) * (EMBED / 4)] = oval;
    op[(size_t)(n + 1 * WPG) * (EMBED / 4)] = oval;
    op[(size_t)(n + 2 * WPG) * (EMBED / 4)] = oval;
    op[(size_t)(n + 3 * WPG) * (EMBED / 4)] = oval;
  }
  for (; n < n1; n += WPG) op[(size_t)n * (EMBED / 4)] = oval;
}

// ======================= legacy 3-kernel fallback =======================
__global__ __launch_bounds__(BLOCK1, 8) void seg_partial(
    const float* __restrict__ x, const int* __restrict__ batch,
    float* __restrict__ partial, int nNodes) {
  const int g  = blockIdx.x >> 2;
  const int p  = blockIdx.x & (P - 1);
  const int t  = threadIdx.x;
  const int q  = t >> 6;
  const int c4 = t & 63;
  int n0, n1;
  find_range(batch, nNodes, g, n0, n1);
  const int cn = n1 - n0;
  const float4* xp = (const float4*)x + (size_t)n0 * (EMBED / 4) + c4;
  const int w = p * NW1 + q;
  float4 a0 = make_float4(0.f, 0.f, 0.f, 0.f);
  int i = w;
  for (; i < cn; i += WPG1) {
    float4 v = xp[(size_t)i * (EMBED / 4)];
    a0.x += v.x; a0.y += v.y; a0.z += v.z; a0.w += v.w;
  }
  __shared__ float4 red4[NW1][EMBED / 4];
  red4[q][c4] = a0;
  __syncthreads();
  if (t < EMBED) {
    const float* rf = (const float*)red4;
    float s = 0.f;
#pragma unroll
    for (int k = 0; k < NW1; ++k) s += rf[k * EMBED + t];
    partial[((size_t)p * NGRAPH + g) * EMBED + t] = s;
  }
}

__global__ __launch_bounds__(EMBED, 1) void graph_rows(
    const float* __restrict__ partial, const int* __restrict__ batch,
    const float* __restrict__ in_w, const float* __restrict__ in_b,
    const float* __restrict__ out_w, const float* __restrict__ out_b,
    float* __restrict__ rows, int nNodes) {
  const int g = blockIdx.x;
  const int t = threadIdx.x;
  int n0, n1;
  find_range(batch, nNodes, g, n0, n1);
  const float inv = 1.0f / fmaxf((float)(n1 - n0), 1.0f);
  __shared__ float sg[EMBED];
  __shared__ float sv[EMBED];
  float s = 0.f;
#pragma unroll
  for (int pp = 0; pp < P; ++pp) s += partial[((size_t)pp * NGRAPH + g) * EMBED + t];
  sg[t] = s * inv;
  __syncthreads();
  float acc = in_b[2 * EMBED + t];
  const float4* wrow = (const float4*)(in_w + (size_t)(2 * EMBED + t) * EMBED);
#pragma unroll 8
  for (int k4 = 0; k4 < EMBED / 4; ++k4) {
    const float4 wv = wrow[k4];
    const int k = k4 * 4;
    acc += sg[k] * wv.x + sg[k + 1] * wv.y + sg[k + 2] * wv.z + sg[k + 3] * wv.w;
  }
  sv[t] = acc;
  __syncthreads();
  float acc2 = out_b[t];
  const float4* wrow2 = (const float4*)(out_w + (size_t)t * EMBED);
#pragma unroll 8
  for (int k4 = 0; k4 < EMBED / 4; ++k4) {
    const float4 wv = wrow2[k4];
    const int k = k4 * 4;
    acc2 += sv[k] * wv.x + sv[k + 1] * wv.y + sv[k + 2] * wv.z + sv[k + 3] * wv.w;
  }
  rows[(size_t)g * EMBED + t] = acc2;
}

__global__ __launch_bounds__(BLOCK3, 8) void bcast(
    const float4* __restrict__ rows4, const int* __restrict__ batch,
    float4* __restrict__ out4, long long total) {
  const long long stride = (long long)gridDim.x * BLOCK3;
  long long i = (long long)blockIdx.x * BLOCK3 + threadIdx.x;
  for (; i < total; i += stride) {
    const int gg = batch[(int)(i >> 6)];
    out4[i] = rows4[(gg << 6) + (int)(i & 63)];
  }
}

// ===========================================================================
extern "C" void kernel_launch(void* const* d_in, const int* in_sizes, int n_in,
                              void* d_out, int out_size, void* d_ws, size_t ws_size,
                              hipStream_t stream) {
  const float* x     = (const float*)d_in[0];
  const float* in_w  = (const float*)d_in[1];
  const float* in_b  = (const float*)d_in[2];
  const float* out_w = (const float*)d_in[3];
  const float* out_b = (const float*)d_in[4];
  const int*   batch = (const int*)d_in[5];
  const int nNodes = in_sizes[5];

  const size_t fCnt  = NGRAPH;                          // counters (ints, 1 KB)
  const size_t fRows = (size_t)NGRAPH * EMBED;          // 256 KB
  const size_t fPart = (size_t)PB * NGRAPH * EMBED;     // 2 MB
  const size_t needFused = (fCnt + fRows + fPart) * sizeof(float);

  if (ws_size >= needFused) {
    int*   cnt     = (int*)d_ws;
    float* rows    = (float*)d_ws + fCnt;
    float* partial = rows + fRows;
    init_cnt<<<1, NGRAPH, 0, stream>>>(cnt);
    fused_all<<<NGRAPH * PB, TBLOCK, 0, stream>>>(
        x, batch, in_w, in_b, out_w, out_b, (float*)d_out, cnt, rows, partial, nNodes);
    return;
  }

  // fallback: round-1 structure (rows in ws; partial spills to d_out scratch)
  const size_t needR = (size_t)NGRAPH * EMBED * sizeof(float);
  const size_t needP = (size_t)P * NGRAPH * EMBED * sizeof(float);
  float* rows = (float*)d_ws;
  float* partial = (ws_size >= needR + needP) ? rows + (size_t)NGRAPH * EMBED
                                              : (float*)d_out;
  seg_partial<<<NGRAPH * P, BLOCK1, 0, stream>>>(x, batch, partial, nNodes);
  graph_rows<<<NGRAPH, EMBED, 0, stream>>>(partial, batch, in_w, in_b,
                                           out_w, out_b, rows, nNodes);
  const long long total = (long long)nNodes * (EMBED / 4);
  bcast<<<NB3, BLOCK3, 0, stream>>>((const float4*)rows, batch,
                                    (float4*)d_out, total);
}

// Round 3
// 400.060 us; speedup vs baseline: 3.0675x; 3.0675x over previous
//
#include <hip/hip_runtime.h>

#define EMBED   256
#define NGRAPH  256
#define P       4                    // partial-sum blocks per graph
#define BLOCK1  512
#define NW1     (BLOCK1 / 64)        // 8 waves per block
#define BLOCK3  256
#define NB3     2048                 // broadcast grid: 8 blocks/CU

__device__ __forceinline__ void find_range(const int* __restrict__ batch,
                                           int nNodes, int g, int& n0, int& n1) {
  int a = 0, b = nNodes;
  while (a < b) { int m = (a + b) >> 1; (batch[m] < g) ? (a = m + 1) : (b = m); }
  n0 = a;
  b = nNodes;
  while (a < b) { int m = (a + b) >> 1; (batch[m] <= g) ? (a = m + 1) : (b = m); }
  n1 = a;
}

// ---------------------------------------------------------------------------
// K1: partial segment sums. Block (g,p) owns a CONTIGUOUS chunk of graph g's
// node range; its 8 waves interleave rows within the chunk. 1024 blocks of
// 8 waves = 32 waves/CU, 1024 long sequential read streams (DRAM-friendly).
// ---------------------------------------------------------------------------
__global__ __launch_bounds__(BLOCK1, 8) void seg_partial(
    const float* __restrict__ x, const int* __restrict__ batch,
    float* __restrict__ partial, int nNodes) {
  const int g  = blockIdx.x >> 2;          // P == 4
  const int p  = blockIdx.x & (P - 1);
  const int t  = threadIdx.x;
  const int q  = t >> 6;                   // wave in block
  const int c4 = t & 63;                   // float4 column

  int n0, n1;
  find_range(batch, nNodes, g, n0, n1);
  const int cnt = n1 - n0;

  // contiguous chunk [c0, c1) of this graph's rows
  const int chunk = (cnt + P - 1) / P;
  const int c0 = min(p * chunk, cnt);
  const int c1 = min(c0 + chunk, cnt);
  const int cc = c1 - c0;

  const float4* xp = (const float4*)x + (size_t)(n0 + c0) * (EMBED / 4) + c4;
  float4 a0 = make_float4(0.f, 0.f, 0.f, 0.f);
  float4 a1 = make_float4(0.f, 0.f, 0.f, 0.f);
  int i = q;
  for (; i + 7 * NW1 < cc; i += 8 * NW1) {
    float4 v0 = xp[(size_t)(i          ) * (EMBED / 4)];
    float4 v1 = xp[(size_t)(i + 1 * NW1) * (EMBED / 4)];
    float4 v2 = xp[(size_t)(i + 2 * NW1) * (EMBED / 4)];
    float4 v3 = xp[(size_t)(i + 3 * NW1) * (EMBED / 4)];
    float4 v4 = xp[(size_t)(i + 4 * NW1) * (EMBED / 4)];
    float4 v5 = xp[(size_t)(i + 5 * NW1) * (EMBED / 4)];
    float4 v6 = xp[(size_t)(i + 6 * NW1) * (EMBED / 4)];
    float4 v7 = xp[(size_t)(i + 7 * NW1) * (EMBED / 4)];
    a0.x += v0.x + v1.x; a0.y += v0.y + v1.y; a0.z += v0.z + v1.z; a0.w += v0.w + v1.w;
    a1.x += v2.x + v3.x; a1.y += v2.y + v3.y; a1.z += v2.z + v3.z; a1.w += v2.w + v3.w;
    a0.x += v4.x + v5.x; a0.y += v4.y + v5.y; a0.z += v4.z + v5.z; a0.w += v4.w + v5.w;
    a1.x += v6.x + v7.x; a1.y += v6.y + v7.y; a1.z += v6.z + v7.z; a1.w += v6.w + v7.w;
  }
  for (; i < cc; i += NW1) {
    float4 v = xp[(size_t)i * (EMBED / 4)];
    a0.x += v.x; a0.y += v.y; a0.z += v.z; a0.w += v.w;
  }
  a0.x += a1.x; a0.y += a1.y; a0.z += a1.z; a0.w += a1.w;

  __shared__ float4 red4[NW1][EMBED / 4];  // layout == float [NW1][EMBED]
  red4[q][c4] = a0;
  __syncthreads();
  if (t < EMBED) {
    const float* rf = (const float*)red4;
    float s = 0.f;
#pragma unroll
    for (int k = 0; k < NW1; ++k) s += rf[k * EMBED + t];
    partial[((size_t)p * NGRAPH + g) * EMBED + t] = s;
  }
}

// ---------------------------------------------------------------------------
// K2: reduce P partials, mean, two 256x256 matvecs -> rows[g][:]. ~5 us.
// ---------------------------------------------------------------------------
__global__ __launch_bounds__(EMBED, 1) void graph_rows(
    const float* __restrict__ partial, const int* __restrict__ batch,
    const float* __restrict__ in_w, const float* __restrict__ in_b,
    const float* __restrict__ out_w, const float* __restrict__ out_b,
    float* __restrict__ rows, int nNodes) {
  const int g = blockIdx.x;
  const int t = threadIdx.x;

  int n0, n1;
  find_range(batch, nNodes, g, n0, n1);
  const float inv = 1.0f / fmaxf((float)(n1 - n0), 1.0f);

  __shared__ float sg[EMBED];
  __shared__ float sv[EMBED];

  float s = 0.f;
#pragma unroll
  for (int pp = 0; pp < P; ++pp)
    s += partial[((size_t)pp * NGRAPH + g) * EMBED + t];
  sg[t] = s * inv;
  __syncthreads();

  float acc = in_b[2 * EMBED + t];
  const float4* wrow = (const float4*)(in_w + (size_t)(2 * EMBED + t) * EMBED);
#pragma unroll 8
  for (int k4 = 0; k4 < EMBED / 4; ++k4) {
    const float4 wv = wrow[k4];
    const int k = k4 * 4;
    acc += sg[k] * wv.x + sg[k + 1] * wv.y + sg[k + 2] * wv.z + sg[k + 3] * wv.w;
  }
  sv[t] = acc;
  __syncthreads();

  float acc2 = out_b[t];
  const float4* wrow2 = (const float4*)(out_w + (size_t)t * EMBED);
#pragma unroll 8
  for (int k4 = 0; k4 < EMBED / 4; ++k4) {
    const float4 wv = wrow2[k4];
    const int k = k4 * 4;
    acc2 += sv[k] * wv.x + sv[k + 1] * wv.y + sv[k + 2] * wv.z + sv[k + 3] * wv.w;
  }
  rows[(size_t)g * EMBED + t] = acc2;
}

// ---------------------------------------------------------------------------
// K3: out[n][:] = rows[batch[n]][:]. Grid-stride, PLAIN float4 stores (the
// 6.7 TB/s harness fill uses plain stores; nt bypassed L2 write-combining
// and regressed round 1). batch[] is wave-uniform per row, L2-hot.
// ---------------------------------------------------------------------------
__global__ __launch_bounds__(BLOCK3, 8) void bcast(
    const float4* __restrict__ rows4, const int* __restrict__ batch,
    float4* __restrict__ out4, long long total) {
  const long long stride = (long long)gridDim.x * BLOCK3;
  long long i = (long long)blockIdx.x * BLOCK3 + threadIdx.x;
  for (; i + 3 * stride < total; i += 4 * stride) {
    const long long i0 = i, i1 = i + stride, i2 = i + 2 * stride, i3 = i + 3 * stride;
    const int g0 = batch[(int)(i0 >> 6)];
    const int g1 = batch[(int)(i1 >> 6)];
    const int g2 = batch[(int)(i2 >> 6)];
    const int g3 = batch[(int)(i3 >> 6)];
    out4[i0] = rows4[(g0 << 6) + (int)(i0 & 63)];
    out4[i1] = rows4[(g1 << 6) + (int)(i1 & 63)];
    out4[i2] = rows4[(g2 << 6) + (int)(i2 & 63)];
    out4[i3] = rows4[(g3 << 6) + (int)(i3 & 63)];
  }
  for (; i < total; i += stride) {
    const int gg = batch[(int)(i >> 6)];
    out4[i] = rows4[(gg << 6) + (int)(i & 63)];
  }
}

// ===========================================================================
extern "C" void kernel_launch(void* const* d_in, const int* in_sizes, int n_in,
                              void* d_out, int out_size, void* d_ws, size_t ws_size,
                              hipStream_t stream) {
  const float* x     = (const float*)d_in[0];
  const float* in_w  = (const float*)d_in[1];
  const float* in_b  = (const float*)d_in[2];
  const float* out_w = (const float*)d_in[3];
  const float* out_b = (const float*)d_in[4];
  const int*   batch = (const int*)d_in[5];
  const int nNodes = in_sizes[5];

  const size_t needR = (size_t)NGRAPH * EMBED * sizeof(float);        // 256 KB
  const size_t needP = (size_t)P * NGRAPH * EMBED * sizeof(float);    // 1 MB

  float* rows = (float*)d_ws;
  float* partial;
  if (ws_size >= needR + needP) {
    partial = rows + (size_t)NGRAPH * EMBED;
  } else {
    // d_out as scratch: written by K1, consumed by K2, then fully
    // overwritten by K3 (stream-ordered, no race).
    partial = (float*)d_out;
  }

  seg_partial<<<NGRAPH * P, BLOCK1, 0, stream>>>(x, batch, partial, nNodes);
  graph_rows<<<NGRAPH, EMBED, 0, stream>>>(partial, batch, in_w, in_b,
                                           out_w, out_b, rows, nNodes);
  const long long total = (long long)nNodes * (EMBED / 4);
  bcast<<<NB3, BLOCK3, 0, stream>>>((const float4*)rows, batch,
                                    (float4*)d_out, total);
}

// Round 4
// 375.163 us; speedup vs baseline: 3.2711x; 1.0664x over previous
//
#include <hip/hip_runtime.h>

#define EMBED   256
#define NGRAPH  256
#define NW      16           // waves per block (was 8 in round 0)
#define BLOCK   (NW * 64)    // 1024 threads

// ---------------------------------------------------------------------------
// Fully fused: one block per graph (batch sorted -> contiguous node range via
// binary search). Identical structure to the round-0 131 us kernel; the ONLY
// change is 1024 threads/block -> 16 waves/CU (2x in-flight memory
// parallelism). No cross-block sync (round-2 lesson: agent-scope flag sync
// is a 1 ms disaster on non-coherent per-XCD L2s).
//   A) streaming segment sum (16 waves, unroll-8 float4 = 8 KB in flight/wave)
//   B) mean + two 256x256 matvecs in threads 0..255 (weights L2-hot)
//   C) broadcast row to the graph's nodes (coalesced 1 KB/wave stores)
// ---------------------------------------------------------------------------
__global__ __launch_bounds__(BLOCK, 4) void fused_kernel(
    const float* __restrict__ x, const int* __restrict__ batch,
    const float* __restrict__ in_w, const float* __restrict__ in_b,
    const float* __restrict__ out_w, const float* __restrict__ out_b,
    float* __restrict__ out, int nNodes) {
  const int g = blockIdx.x;
  const int t = threadIdx.x;
  const int q  = t >> 6;   // wave id 0..15
  const int c4 = t & 63;   // float4 column 0..63

  // node range [n0, n1) for graph g
  int n0, n1;
  { int a = 0, b = nNodes;
    while (a < b) { int m = (a + b) >> 1; (batch[m] < g) ? (a = m + 1) : (b = m); }
    n0 = a; }
  { int a = n0, b = nNodes;
    while (a < b) { int m = (a + b) >> 1; (batch[m] <= g) ? (a = m + 1) : (b = m); }
    n1 = a; }
  const int cnt = n1 - n0;

  // ---- A) segment sum: wave q handles rows n0+q, n0+q+NW, ... ----
  const float4* xp = (const float4*)x + (size_t)n0 * (EMBED / 4) + c4;
  float4 a0 = make_float4(0.f, 0.f, 0.f, 0.f);
  float4 a1 = make_float4(0.f, 0.f, 0.f, 0.f);
  int i = q;
  for (; i + 7 * NW < cnt; i += 8 * NW) {
    float4 v0 = xp[(size_t)(i         ) * (EMBED / 4)];
    float4 v1 = xp[(size_t)(i + 1 * NW) * (EMBED / 4)];
    float4 v2 = xp[(size_t)(i + 2 * NW) * (EMBED / 4)];
    float4 v3 = xp[(size_t)(i + 3 * NW) * (EMBED / 4)];
    float4 v4 = xp[(size_t)(i + 4 * NW) * (EMBED / 4)];
    float4 v5 = xp[(size_t)(i + 5 * NW) * (EMBED / 4)];
    float4 v6 = xp[(size_t)(i + 6 * NW) * (EMBED / 4)];
    float4 v7 = xp[(size_t)(i + 7 * NW) * (EMBED / 4)];
    a0.x += v0.x + v1.x; a0.y += v0.y + v1.y; a0.z += v0.z + v1.z; a0.w += v0.w + v1.w;
    a1.x += v2.x + v3.x; a1.y += v2.y + v3.y; a1.z += v2.z + v3.z; a1.w += v2.w + v3.w;
    a0.x += v4.x + v5.x; a0.y += v4.y + v5.y; a0.z += v4.z + v5.z; a0.w += v4.w + v5.w;
    a1.x += v6.x + v7.x; a1.y += v6.y + v7.y; a1.z += v6.z + v7.z; a1.w += v6.w + v7.w;
  }
  for (; i < cnt; i += NW) {
    float4 v = xp[(size_t)i * (EMBED / 4)];
    a0.x += v.x; a0.y += v.y; a0.z += v.z; a0.w += v.w;
  }
  a0.x += a1.x; a0.y += a1.y; a0.z += a1.z; a0.w += a1.w;

  // ---- cross-wave reduce + mean ----
  __shared__ float4 red4[NW][EMBED / 4];   // layout == float [NW][EMBED]
  __shared__ float sg[EMBED];
  __shared__ float sv[EMBED];
  __shared__ float so[EMBED];
  red4[q][c4] = a0;
  __syncthreads();

  const float inv = 1.0f / fmaxf((float)cnt, 1.0f);
  if (t < EMBED) {
    const float* rf = (const float*)red4;
    float s = 0.f;
#pragma unroll
    for (int k = 0; k < NW; ++k) s += rf[k * EMBED + t];
    sg[t] = s * inv;
  }
  __syncthreads();

  // ---- B) matvec 1: v = mean @ Wv^T + bv (thread t -> column t) ----
  if (t < EMBED) {
    float acc = in_b[2 * EMBED + t];
    const float4* wrow = (const float4*)(in_w + (size_t)(2 * EMBED + t) * EMBED);
#pragma unroll 8
    for (int k4 = 0; k4 < EMBED / 4; ++k4) {
      const float4 w = wrow[k4];
      const int k = k4 * 4;
      acc += sg[k] * w.x + sg[k + 1] * w.y + sg[k + 2] * w.z + sg[k + 3] * w.w;
    }
    sv[t] = acc;
  }
  __syncthreads();

  // ---- matvec 2: row = v @ W2^T + b2 ----
  if (t < EMBED) {
    float acc = out_b[t];
    const float4* wrow = (const float4*)(out_w + (size_t)t * EMBED);
#pragma unroll 8
    for (int k4 = 0; k4 < EMBED / 4; ++k4) {
      const float4 w = wrow[k4];
      const int k = k4 * 4;
      acc += sv[k] * w.x + sv[k + 1] * w.y + sv[k + 2] * w.z + sv[k + 3] * w.w;
    }
    so[t] = acc;
  }
  __syncthreads();

  // ---- C) broadcast the graph row to all its nodes ----
  const float4 oval = ((const float4*)so)[c4];
  float4* op = (float4*)out + c4;
  int n = n0 + q;
  for (; n + 3 * NW < n1; n += 4 * NW) {
    op[(size_t)(n         ) * (EMBED / 4)] = oval;
    op[(size_t)(n + 1 * NW) * (EMBED / 4)] = oval;
    op[(size_t)(n + 2 * NW) * (EMBED / 4)] = oval;
    op[(size_t)(n + 3 * NW) * (EMBED / 4)] = oval;
  }
  for (; n < n1; n += NW) {
    op[(size_t)n * (EMBED / 4)] = oval;
  }
}

extern "C" void kernel_launch(void* const* d_in, const int* in_sizes, int n_in,
                              void* d_out, int out_size, void* d_ws, size_t ws_size,
                              hipStream_t stream) {
  const float* x     = (const float*)d_in[0];
  const float* in_w  = (const float*)d_in[1];
  const float* in_b  = (const float*)d_in[2];
  const float* out_w = (const float*)d_in[3];
  const float* out_b = (const float*)d_in[4];
  const int*   batch = (const int*)d_in[5];
  const int nNodes = in_sizes[5];

  fused_kernel<<<NGRAPH, BLOCK, 0, stream>>>(x, batch, in_w, in_b, out_w, out_b,
                                             (float*)d_out, nNodes);
}

// Round 5
// 369.099 us; speedup vs baseline: 3.3248x; 1.0164x over previous
//
#include <hip/hip_runtime.h>

#define EMBED   256
#define NGRAPH  256
#define NW      16           // waves per block
#define BLOCK   (NW * 64)    // 1024 threads

typedef float f32x4 __attribute__((ext_vector_type(4)));

// ---------------------------------------------------------------------------
// Fully fused: one block per graph (batch sorted -> contiguous node range via
// binary search). Identical to the round-4 kernel EXCEPT phase C uses
// nontemporal stores: the 200 MB out-stream bypasses cache so it cannot
// evict x (205 MB) from the 256 MB Infinity Cache. Round-4 A/B showed the
// kernel is not occupancy-limited; FETCH_SIZE=103MB showed half of x was
// L3-resident and the other half was being evicted by our own write phase.
//   A) streaming segment sum (16 waves, unroll-8 float4)
//   B) mean + two 256x256 matvecs in threads 0..255 (weights L2-hot)
//   C) nontemporal broadcast of the graph row (coalesced 1 KB/wave stores)
// ---------------------------------------------------------------------------
__global__ __launch_bounds__(BLOCK, 4) void fused_kernel(
    const float* __restrict__ x, const int* __restrict__ batch,
    const float* __restrict__ in_w, const float* __restrict__ in_b,
    const float* __restrict__ out_w, const float* __restrict__ out_b,
    float* __restrict__ out, int nNodes) {
  const int g = blockIdx.x;
  const int t = threadIdx.x;
  const int q  = t >> 6;   // wave id 0..15
  const int c4 = t & 63;   // float4 column 0..63

  // node range [n0, n1) for graph g
  int n0, n1;
  { int a = 0, b = nNodes;
    while (a < b) { int m = (a + b) >> 1; (batch[m] < g) ? (a = m + 1) : (b = m); }
    n0 = a; }
  { int a = n0, b = nNodes;
    while (a < b) { int m = (a + b) >> 1; (batch[m] <= g) ? (a = m + 1) : (b = m); }
    n1 = a; }
  const int cnt = n1 - n0;

  // ---- A) segment sum: wave q handles rows n0+q, n0+q+NW, ... ----
  const float4* xp = (const float4*)x + (size_t)n0 * (EMBED / 4) + c4;
  float4 a0 = make_float4(0.f, 0.f, 0.f, 0.f);
  float4 a1 = make_float4(0.f, 0.f, 0.f, 0.f);
  int i = q;
  for (; i + 7 * NW < cnt; i += 8 * NW) {
    float4 v0 = xp[(size_t)(i         ) * (EMBED / 4)];
    float4 v1 = xp[(size_t)(i + 1 * NW) * (EMBED / 4)];
    float4 v2 = xp[(size_t)(i + 2 * NW) * (EMBED / 4)];
    float4 v3 = xp[(size_t)(i + 3 * NW) * (EMBED / 4)];
    float4 v4 = xp[(size_t)(i + 4 * NW) * (EMBED / 4)];
    float4 v5 = xp[(size_t)(i + 5 * NW) * (EMBED / 4)];
    float4 v6 = xp[(size_t)(i + 6 * NW) * (EMBED / 4)];
    float4 v7 = xp[(size_t)(i + 7 * NW) * (EMBED / 4)];
    a0.x += v0.x + v1.x; a0.y += v0.y + v1.y; a0.z += v0.z + v1.z; a0.w += v0.w + v1.w;
    a1.x += v2.x + v3.x; a1.y += v2.y + v3.y; a1.z += v2.z + v3.z; a1.w += v2.w + v3.w;
    a0.x += v4.x + v5.x; a0.y += v4.y + v5.y; a0.z += v4.z + v5.z; a0.w += v4.w + v5.w;
    a1.x += v6.x + v7.x; a1.y += v6.y + v7.y; a1.z += v6.z + v7.z; a1.w += v6.w + v7.w;
  }
  for (; i < cnt; i += NW) {
    float4 v = xp[(size_t)i * (EMBED / 4)];
    a0.x += v.x; a0.y += v.y; a0.z += v.z; a0.w += v.w;
  }
  a0.x += a1.x; a0.y += a1.y; a0.z += a1.z; a0.w += a1.w;

  // ---- cross-wave reduce + mean ----
  __shared__ float4 red4[NW][EMBED / 4];   // layout == float [NW][EMBED]
  __shared__ float sg[EMBED];
  __shared__ float sv[EMBED];
  __shared__ float so[EMBED];
  red4[q][c4] = a0;
  __syncthreads();

  const float inv = 1.0f / fmaxf((float)cnt, 1.0f);
  if (t < EMBED) {
    const float* rf = (const float*)red4;
    float s = 0.f;
#pragma unroll
    for (int k = 0; k < NW; ++k) s += rf[k * EMBED + t];
    sg[t] = s * inv;
  }
  __syncthreads();

  // ---- B) matvec 1: v = mean @ Wv^T + bv (thread t -> column t) ----
  if (t < EMBED) {
    float acc = in_b[2 * EMBED + t];
    const float4* wrow = (const float4*)(in_w + (size_t)(2 * EMBED + t) * EMBED);
#pragma unroll 8
    for (int k4 = 0; k4 < EMBED / 4; ++k4) {
      const float4 w = wrow[k4];
      const int k = k4 * 4;
      acc += sg[k] * w.x + sg[k + 1] * w.y + sg[k + 2] * w.z + sg[k + 3] * w.w;
    }
    sv[t] = acc;
  }
  __syncthreads();

  // ---- matvec 2: row = v @ W2^T + b2 ----
  if (t < EMBED) {
    float acc = out_b[t];
    const float4* wrow = (const float4*)(out_w + (size_t)t * EMBED);
#pragma unroll 8
    for (int k4 = 0; k4 < EMBED / 4; ++k4) {
      const float4 w = wrow[k4];
      const int k = k4 * 4;
      acc += sv[k] * w.x + sv[k + 1] * w.y + sv[k + 2] * w.z + sv[k + 3] * w.w;
    }
    so[t] = acc;
  }
  __syncthreads();

  // ---- C) nontemporal broadcast of the graph row to all its nodes ----
  const f32x4 oval = *(const f32x4*)&((const float4*)so)[c4];
  f32x4* op = (f32x4*)out + c4;
  int n = n0 + q;
  for (; n + 3 * NW < n1; n += 4 * NW) {
    __builtin_nontemporal_store(oval, op + (size_t)(n         ) * (EMBED / 4));
    __builtin_nontemporal_store(oval, op + (size_t)(n + 1 * NW) * (EMBED / 4));
    __builtin_nontemporal_store(oval, op + (size_t)(n + 2 * NW) * (EMBED / 4));
    __builtin_nontemporal_store(oval, op + (size_t)(n + 3 * NW) * (EMBED / 4));
  }
  for (; n < n1; n += NW) {
    __builtin_nontemporal_store(oval, op + (size_t)n * (EMBED / 4));
  }
}

extern "C" void kernel_launch(void* const* d_in, const int* in_sizes, int n_in,
                              void* d_out, int out_size, void* d_ws, size_t ws_size,
                              hipStream_t stream) {
  const float* x     = (const float*)d_in[0];
  const float* in_w  = (const float*)d_in[1];
  const float* in_b  = (const float*)d_in[2];
  const float* out_w = (const float*)d_in[3];
  const float* out_b = (const float*)d_in[4];
  const int*   batch = (const int*)d_in[5];
  const int nNodes = in_sizes[5];

  fused_kernel<<<NGRAPH, BLOCK, 0, stream>>>(x, batch, in_w, in_b, out_w, out_b,
                                             (float*)d_out, nNodes);
}

// Round 6
// 351.100 us; speedup vs baseline: 3.4953x; 1.0513x over previous
//
#include <hip/hip_runtime.h>

#define EMBED   256
#define NGRAPH  256
#define NW      16           // waves per block
#define BLOCK   (NW * 64)    // 1024 threads

typedef float f32x4 __attribute__((ext_vector_type(4)));

// ---------------------------------------------------------------------------
// One block per graph (batch sorted -> contiguous node range via binary
// search). Round-6 change: phase A only.
//  - each WAVE owns a CONTIGUOUS chunk of the graph's rows (16 streams/CU,
//    DRAM page-local) instead of a 16-row interleave (8 in-flight loads
//    spread over 113 KB).
//  - unroll 16 -> 16 KB in flight per wave.
//  - nontemporal loads: streaming x must not allocate in L2/L1 (matches the
//    6.7 TB/s fill, which also doesn't allocate on its write path).
// Phases B and C are byte-identical to round 5 (nt stores kept: neutral).
// Evidence base: round-4 A/B killed occupancy/MLP theories; FETCH_SIZE is
// half of |x| == gfx94x-formula 2x undercount -> x fully cold each iter;
// write phase ~= fill speed; read phase ~2.3 TB/s is the entire problem.
// ---------------------------------------------------------------------------
__global__ __launch_bounds__(BLOCK, 4) void fused_kernel(
    const float* __restrict__ x, const int* __restrict__ batch,
    const float* __restrict__ in_w, const float* __restrict__ in_b,
    const float* __restrict__ out_w, const float* __restrict__ out_b,
    float* __restrict__ out, int nNodes) {
  const int g = blockIdx.x;
  const int t = threadIdx.x;
  const int q  = t >> 6;   // wave id 0..15
  const int c4 = t & 63;   // float4 column 0..63

  // node range [n0, n1) for graph g
  int n0, n1;
  { int a = 0, b = nNodes;
    while (a < b) { int m = (a + b) >> 1; (batch[m] < g) ? (a = m + 1) : (b = m); }
    n0 = a; }
  { int a = n0, b = nNodes;
    while (a < b) { int m = (a + b) >> 1; (batch[m] <= g) ? (a = m + 1) : (b = m); }
    n1 = a; }
  const int cnt = n1 - n0;

  // ---- A) segment sum: wave q owns contiguous rows [w0, w1) ----
  const int chunk = (cnt + NW - 1) / NW;
  const int w0 = min(q * chunk, cnt);
  const int w1 = min(w0 + chunk, cnt);
  const int m  = w1 - w0;

  const f32x4* xq = (const f32x4*)x + (size_t)(n0 + w0) * (EMBED / 4) + c4;
  f32x4 a0 = 0.f, a1 = 0.f, a2 = 0.f, a3 = 0.f;
  int i = 0;
  for (; i + 15 < m; i += 16) {
    const f32x4* p = xq + (size_t)i * (EMBED / 4);
    f32x4 v0  = __builtin_nontemporal_load(p +  0 * (EMBED / 4));
    f32x4 v1  = __builtin_nontemporal_load(p +  1 * (EMBED / 4));
    f32x4 v2  = __builtin_nontemporal_load(p +  2 * (EMBED / 4));
    f32x4 v3  = __builtin_nontemporal_load(p +  3 * (EMBED / 4));
    f32x4 v4  = __builtin_nontemporal_load(p +  4 * (EMBED / 4));
    f32x4 v5  = __builtin_nontemporal_load(p +  5 * (EMBED / 4));
    f32x4 v6  = __builtin_nontemporal_load(p +  6 * (EMBED / 4));
    f32x4 v7  = __builtin_nontemporal_load(p +  7 * (EMBED / 4));
    f32x4 v8  = __builtin_nontemporal_load(p +  8 * (EMBED / 4));
    f32x4 v9  = __builtin_nontemporal_load(p +  9 * (EMBED / 4));
    f32x4 v10 = __builtin_nontemporal_load(p + 10 * (EMBED / 4));
    f32x4 v11 = __builtin_nontemporal_load(p + 11 * (EMBED / 4));
    f32x4 v12 = __builtin_nontemporal_load(p + 12 * (EMBED / 4));
    f32x4 v13 = __builtin_nontemporal_load(p + 13 * (EMBED / 4));
    f32x4 v14 = __builtin_nontemporal_load(p + 14 * (EMBED / 4));
    f32x4 v15 = __builtin_nontemporal_load(p + 15 * (EMBED / 4));
    a0 += v0;  a1 += v1;  a2 += v2;  a3 += v3;
    a0 += v4;  a1 += v5;  a2 += v6;  a3 += v7;
    a0 += v8;  a1 += v9;  a2 += v10; a3 += v11;
    a0 += v12; a1 += v13; a2 += v14; a3 += v15;
  }
  for (; i < m; ++i)
    a0 += __builtin_nontemporal_load(xq + (size_t)i * (EMBED / 4));
  const f32x4 asum = (a0 + a1) + (a2 + a3);

  // ---- cross-wave reduce + mean ----
  __shared__ f32x4 red4[NW][EMBED / 4];    // layout == float [NW][EMBED]
  __shared__ float sg[EMBED];
  __shared__ float sv[EMBED];
  __shared__ float so[EMBED];
  red4[q][c4] = asum;
  __syncthreads();

  const float inv = 1.0f / fmaxf((float)cnt, 1.0f);
  if (t < EMBED) {
    const float* rf = (const float*)red4;
    float s = 0.f;
#pragma unroll
    for (int k = 0; k < NW; ++k) s += rf[k * EMBED + t];
    sg[t] = s * inv;
  }
  __syncthreads();

  // ---- B) matvec 1: v = mean @ Wv^T + bv (thread t -> column t) ----
  if (t < EMBED) {
    float acc = in_b[2 * EMBED + t];
    const float4* wrow = (const float4*)(in_w + (size_t)(2 * EMBED + t) * EMBED);
#pragma unroll 8
    for (int k4 = 0; k4 < EMBED / 4; ++k4) {
      const float4 w = wrow[k4];
      const int k = k4 * 4;
      acc += sg[k] * w.x + sg[k + 1] * w.y + sg[k + 2] * w.z + sg[k + 3] * w.w;
    }
    sv[t] = acc;
  }
  __syncthreads();

  // ---- matvec 2: row = v @ W2^T + b2 ----
  if (t < EMBED) {
    float acc = out_b[t];
    const float4* wrow = (const float4*)(out_w + (size_t)t * EMBED);
#pragma unroll 8
    for (int k4 = 0; k4 < EMBED / 4; ++k4) {
      const float4 w = wrow[k4];
      const int k = k4 * 4;
      acc += sv[k] * w.x + sv[k + 1] * w.y + sv[k + 2] * w.z + sv[k + 3] * w.w;
    }
    so[t] = acc;
  }
  __syncthreads();

  // ---- C) nontemporal broadcast of the graph row to all its nodes ----
  const f32x4 oval = *(const f32x4*)&((const float*)so)[c4 * 4];
  f32x4* op = (f32x4*)out + c4;
  int n = n0 + q;
  for (; n + 3 * NW < n1; n += 4 * NW) {
    __builtin_nontemporal_store(oval, op + (size_t)(n         ) * (EMBED / 4));
    __builtin_nontemporal_store(oval, op + (size_t)(n + 1 * NW) * (EMBED / 4));
    __builtin_nontemporal_store(oval, op + (size_t)(n + 2 * NW) * (EMBED / 4));
    __builtin_nontemporal_store(oval, op + (size_t)(n + 3 * NW) * (EMBED / 4));
  }
  for (; n < n1; n += NW) {
    __builtin_nontemporal_store(oval, op + (size_t)n * (EMBED / 4));
  }
}

extern "C" void kernel_launch(void* const* d_in, const int* in_sizes, int n_in,
                              void* d_out, int out_size, void* d_ws, size_t ws_size,
                              hipStream_t stream) {
  const float* x     = (const float*)d_in[0];
  const float* in_w  = (const float*)d_in[1];
  const float* in_b  = (const float*)d_in[2];
  const float* out_w = (const float*)d_in[3];
  const float* out_b = (const float*)d_in[4];
  const int*   batch = (const int*)d_in[5];
  const int nNodes = in_sizes[5];

  fused_kernel<<<NGRAPH, BLOCK, 0, stream>>>(x, batch, in_w, in_b, out_w, out_b,
                                             (float*)d_out, nNodes);
}